// Round 1
// baseline (702.028 us; speedup 1.0000x reference)
//
#include <hip/hip_runtime.h>
#include <hip/hip_bf16.h>

#define B_ 4
#define L_ 2052
#define C_ 1024
#define H_ 16
#define D_ 64
#define NREG_ 4
#define M_ (B_*L_)   // 8208

typedef short bf16x8 __attribute__((ext_vector_type(8)));
typedef float f32x4 __attribute__((ext_vector_type(4)));
typedef __hip_bfloat16 bf16;

#define MFMA(a,b,c) __builtin_amdgcn_mfma_f32_16x16x32_bf16(a,b,c,0,0,0)

__device__ inline float b2f(bf16 v){ return __bfloat162float(v); }
__device__ inline bf16  f2b(float v){ return __float2bfloat16(v); }

// ---------------- x -> bf16 hi/lo split ----------------
__global__ __launch_bounds__(256)
void cvt_split(const float* __restrict__ in, bf16* __restrict__ hi,
               bf16* __restrict__ lo, int n)
{
    int i = (blockIdx.x*256 + threadIdx.x)*4;
    if (i >= n) return;
    float4 v = *(const float4*)(in + i);
    int2 hraw, lraw;
    bf16* hp = (bf16*)&hraw;
    bf16* lp = (bf16*)&lraw;
    float vv[4] = {v.x, v.y, v.z, v.w};
    #pragma unroll
    for (int j=0;j<4;++j){
        bf16 h = f2b(vv[j]);
        hp[j] = h;
        lp[j] = f2b(vv[j] - b2f(h));
    }
    *(int2*)(hi + i) = hraw;
    *(int2*)(lo + i) = lraw;
}

// ---------------- fp32 [R][Cc] -> bf16 transposed [Cc][R] ----------------
__global__ __launch_bounds__(256)
void transpose_cvt(const float* __restrict__ in, bf16* __restrict__ out,
                   int R, int Cc)
{
    __shared__ bf16 t[32][33];
    int bx = blockIdx.x * 32;   // col tile of input
    int by = blockIdx.y * 32;   // row tile of input
    int tx = threadIdx.x;       // 0..31
    int ty = threadIdx.y;       // 0..7
    #pragma unroll
    for (int i=0;i<4;++i){
        int r = by + ty + i*8;
        int c = bx + tx;
        t[ty+i*8][tx] = f2b(in[(size_t)r*Cc + c]);
    }
    __syncthreads();
    #pragma unroll
    for (int i=0;i<4;++i){
        int r = bx + ty + i*8;  // out row = input col
        int c = by + tx;        // out col = input row
        out[(size_t)r*R + c] = t[tx][ty+i*8];
    }
}

// ---------------- GEMM: A[M][K] (+optional lo) x Bt[N][K] -> C[M][N] ----------------
template<typename OutT, bool SPLIT>
__global__ __launch_bounds__(256)
void gemm_bt(const bf16* __restrict__ A, const bf16* __restrict__ Alo,
             const bf16* __restrict__ Bt, const float* __restrict__ bias,
             OutT* __restrict__ C, int M, int N, int K)
{
    __shared__ bf16 As[128*40];
    __shared__ bf16 Als[SPLIT ? 128*40 : 8];
    __shared__ bf16 Bs[128*40];

    int tid  = threadIdx.x;
    int lane = tid & 63, wave = tid >> 6;
    int wm = (wave>>1)*64, wn = (wave&1)*64;
    int bm = blockIdx.y*128, bn = blockIdx.x*128;
    int lrow = lane & 15, lk8 = (lane>>4)*8;
    int quad = lane >> 4;

    f32x4 acc[4][4] = {};

    int r0 = tid >> 2;          // 0..63 (two iters cover 128 rows)
    int c0 = (tid & 3) * 8;     // 0,8,16,24

    for (int k0 = 0; k0 < K; k0 += 32) {
        #pragma unroll
        for (int it=0; it<2; ++it) {
            int r = r0 + it*64;
            int ga = bm + r;
            int4 va = {0,0,0,0}, vl = {0,0,0,0}, vb = {0,0,0,0};
            if (ga < M) {
                va = *(const int4*)(A + (size_t)ga*K + k0 + c0);
                if constexpr (SPLIT)
                    vl = *(const int4*)(Alo + (size_t)ga*K + k0 + c0);
            }
            int gb = bn + r;
            if (gb < N) vb = *(const int4*)(Bt + (size_t)gb*K + k0 + c0);
            *(int4*)(&As[r*40 + c0]) = va;
            if constexpr (SPLIT) *(int4*)(&Als[r*40 + c0]) = vl;
            *(int4*)(&Bs[r*40 + c0]) = vb;
        }
        __syncthreads();
        bf16x8 a[4], al[4], b[4];
        #pragma unroll
        for (int i=0;i<4;++i){
            a[i] = *(const bf16x8*)(&As[(wm+i*16+lrow)*40 + lk8]);
            if constexpr (SPLIT)
                al[i] = *(const bf16x8*)(&Als[(wm+i*16+lrow)*40 + lk8]);
            b[i] = *(const bf16x8*)(&Bs[(wn+i*16+lrow)*40 + lk8]);
        }
        #pragma unroll
        for (int mi=0;mi<4;++mi)
            #pragma unroll
            for (int ni=0;ni<4;++ni){
                acc[mi][ni] = MFMA(a[mi], b[ni], acc[mi][ni]);
                if constexpr (SPLIT)
                    acc[mi][ni] = MFMA(al[mi], b[ni], acc[mi][ni]);
            }
        __syncthreads();
    }

    #pragma unroll
    for (int ni=0;ni<4;++ni){
        int col = bn + wn + ni*16 + lrow;
        float bv = bias[col];
        #pragma unroll
        for (int mi=0;mi<4;++mi){
            int rowb = bm + wm + mi*16 + quad*4;
            #pragma unroll
            for (int r=0;r<4;++r){
                int row = rowb + r;
                if (row < M) {
                    float v = acc[mi][ni][r] + bv;
                    if constexpr (sizeof(OutT)==4) C[(size_t)row*N + col] = v;
                    else                           C[(size_t)row*N + col] = f2b(v);
                }
            }
        }
    }
}

// ---------------- RoPE in-place on q,k of qkv [M][3072] bf16 ----------------
__global__ __launch_bounds__(256)
void rope_kernel(bf16* __restrict__ qkv, const float* __restrict__ rope)
{
    int idx = blockIdx.x*256 + threadIdx.x;
    int d = idx & 31;
    int h = (idx >> 5) & 15;
    int m = idx >> 9;
    if (m >= M_) return;
    int l = m % L_;
    if (l < NREG_) return;
    const float* cp = rope + (size_t)(l - NREG_)*D_;
    const float* sp = rope + (size_t)(L_ - NREG_)*D_ + (size_t)(l - NREG_)*D_;
    float c0 = cp[d], c1 = cp[d+32], s0 = sp[d], s1 = sp[d+32];
    size_t base = (size_t)m*3072 + h*64;
    // q
    {
        float a = b2f(qkv[base + d]), b = b2f(qkv[base + d + 32]);
        qkv[base + d]      = f2b(a*c0 - b*s0);
        qkv[base + d + 32] = f2b(b*c1 + a*s1);
    }
    // k
    {
        size_t kb = base + 1024;
        float a = b2f(qkv[kb + d]), b = b2f(qkv[kb + d + 32]);
        qkv[kb + d]      = f2b(a*c0 - b*s0);
        qkv[kb + d + 32] = f2b(b*c1 + a*s1);
    }
}

// ---------------- flash attention ----------------
// grid: (ceil(L/128), B*H), block 256 (4 waves, 32 Q-rows each)
__global__ __launch_bounds__(256)
void attn_kernel(const bf16* __restrict__ qkv, bf16* __restrict__ out)
{
    __shared__ bf16 Qs[128*72];
    __shared__ bf16 Ks[64*72];
    __shared__ bf16 Vts[64*72];
    __shared__ bf16 Ps[4*32*72];

    int tid = threadIdx.x, lane = tid & 63, wave = tid >> 6;
    int lrow = lane & 15, lk8 = (lane>>4)*8, quad = lane >> 4;
    int qt = blockIdx.x;
    int bh = blockIdx.y;
    int b  = bh >> 4, h = bh & 15;
    size_t rowbase = (size_t)b * L_;
    int q0 = qt * 128;

    // stage Q tile
    #pragma unroll
    for (int it=0; it<4; ++it){
        int i = tid + it*256;       // 0..1023
        int r = i >> 3;             // 0..127
        int c = (i & 7) * 8;
        int lq = q0 + r;
        int4 v = {0,0,0,0};
        if (lq < L_) v = *(const int4*)(qkv + (rowbase + lq)*3072 + h*64 + c);
        *(int4*)(&Qs[r*72 + c]) = v;
    }
    __syncthreads();

    bf16x8 qf[2][2];
    #pragma unroll
    for (int mi=0;mi<2;++mi)
        #pragma unroll
        for (int s=0;s<2;++s)
            qf[mi][s] = *(const bf16x8*)(&Qs[(wave*32 + mi*16 + lrow)*72 + s*32 + lk8]);

    float mst[2][4], lst[2][4];
    f32x4 o_[2][4] = {};
    #pragma unroll
    for (int mi=0;mi<2;++mi)
        #pragma unroll
        for (int r=0;r<4;++r){ mst[mi][r] = -3.0e38f; lst[mi][r] = 0.f; }

    bf16* pw = &Ps[wave*32*72];
    const int nkt = (L_ + 63) / 64;   // 33

    for (int kt = 0; kt < nkt; ++kt) {
        __syncthreads();   // protect Ks/Vts from prior-iter readers
        // stage K (row-major) and V (transposed)
        #pragma unroll
        for (int it=0; it<2; ++it){
            int i = tid + it*256;    // 0..511
            int r = i >> 3;          // key row 0..63
            int c = (i & 7) * 8;     // d chunk
            int lk = kt*64 + r;
            int4 vk = {0,0,0,0}, vv = {0,0,0,0};
            if (lk < L_) {
                size_t rb = (rowbase + lk)*3072 + h*64 + c;
                vk = *(const int4*)(qkv + rb + 1024);
                vv = *(const int4*)(qkv + rb + 2048);
            }
            *(int4*)(&Ks[r*72 + c]) = vk;
            bf16* tv = (bf16*)&vv;
            #pragma unroll
            for (int j=0;j<8;++j) Vts[(c+j)*72 + r] = tv[j];
        }
        __syncthreads();

        // S = Q K^T
        f32x4 sf[2][4];
        {
            bf16x8 kf[4][2];
            #pragma unroll
            for (int ni=0;ni<4;++ni)
                #pragma unroll
                for (int s=0;s<2;++s)
                    kf[ni][s] = *(const bf16x8*)(&Ks[(ni*16+lrow)*72 + s*32 + lk8]);
            #pragma unroll
            for (int mi=0;mi<2;++mi)
                #pragma unroll
                for (int ni=0;ni<4;++ni){
                    f32x4 t = {};
                    t = MFMA(qf[mi][0], kf[ni][0], t);
                    t = MFMA(qf[mi][1], kf[ni][1], t);
                    sf[mi][ni] = t;
                }
        }
        // scale + mask tail keys
        #pragma unroll
        for (int ni=0;ni<4;++ni){
            int col = kt*64 + ni*16 + lrow;
            bool valid = col < L_;
            #pragma unroll
            for (int mi=0;mi<2;++mi)
                #pragma unroll
                for (int r=0;r<4;++r){
                    float v = sf[mi][ni][r]*0.125f;
                    sf[mi][ni][r] = valid ? v : -3.0e38f;
                }
        }
        // online softmax per row (row = quad*4+r within each 16-tile)
        float alpha[2][4];
        #pragma unroll
        for (int mi=0;mi<2;++mi)
            #pragma unroll
            for (int r=0;r<4;++r){
                float mx = fmaxf(fmaxf(sf[mi][0][r], sf[mi][1][r]),
                                 fmaxf(sf[mi][2][r], sf[mi][3][r]));
                #pragma unroll
                for (int o=1;o<16;o<<=1) mx = fmaxf(mx, __shfl_xor(mx, o));
                float mnew = fmaxf(mst[mi][r], mx);
                alpha[mi][r] = __expf(mst[mi][r] - mnew);
                mst[mi][r] = mnew;
                float rs = 0.f;
                #pragma unroll
                for (int ni=0;ni<4;++ni){
                    float p = __expf(sf[mi][ni][r] - mnew);
                    sf[mi][ni][r] = p;
                    rs += p;
                }
                #pragma unroll
                for (int o=1;o<16;o<<=1) rs += __shfl_xor(rs, o);
                lst[mi][r] = lst[mi][r]*alpha[mi][r] + rs;
            }
        // P (C-layout) -> LDS -> A-layout
        #pragma unroll
        for (int mi=0;mi<2;++mi)
            #pragma unroll
            for (int ni=0;ni<4;++ni)
                #pragma unroll
                for (int r=0;r<4;++r)
                    pw[(mi*16 + quad*4 + r)*72 + ni*16 + lrow] = f2b(sf[mi][ni][r]);
        __syncthreads();
        // O = O*alpha + P V
        bf16x8 vf[4][2], pf[2][2];
        #pragma unroll
        for (int ni=0;ni<4;++ni)
            #pragma unroll
            for (int s=0;s<2;++s)
                vf[ni][s] = *(const bf16x8*)(&Vts[(ni*16+lrow)*72 + s*32 + lk8]);
        #pragma unroll
        for (int mi=0;mi<2;++mi)
            #pragma unroll
            for (int s=0;s<2;++s)
                pf[mi][s] = *(const bf16x8*)(&pw[(mi*16 + lrow)*72 + s*32 + lk8]);
        #pragma unroll
        for (int mi=0;mi<2;++mi)
            #pragma unroll
            for (int ni=0;ni<4;++ni){
                f32x4 t = o_[mi][ni];
                #pragma unroll
                for (int r=0;r<4;++r) t[r] *= alpha[mi][r];
                t = MFMA(pf[mi][0], vf[ni][0], t);
                t = MFMA(pf[mi][1], vf[ni][1], t);
                o_[mi][ni] = t;
            }
    }

    // finalize + store: out[b*L+lq][h*64 + d]
    #pragma unroll
    for (int mi=0;mi<2;++mi)
        #pragma unroll
        for (int r=0;r<4;++r){
            int lq = q0 + wave*32 + mi*16 + quad*4 + r;
            if (lq < L_){
                float inv = 1.f / lst[mi][r];
                size_t base = (rowbase + lq)*1024 + h*64;
                #pragma unroll
                for (int ni=0;ni<4;++ni)
                    out[base + ni*16 + lrow] = f2b(o_[mi][ni][r]*inv);
            }
        }
}

// ---------------- LayerNorm (per row of [M][1024]) -> bf16 ----------------
__global__ __launch_bounds__(256)
void ln_kernel(const bf16* __restrict__ in, const float* __restrict__ gamma,
               const float* __restrict__ beta, bf16* __restrict__ out)
{
    int row = blockIdx.x;
    int tid = threadIdx.x;
    int wave = tid >> 6, lane = tid & 63;
    int2 raw = *(const int2*)(in + (size_t)row*1024 + tid*4);
    const bf16* loc = (const bf16*)&raw;
    float v[4];
    float s = 0.f, q = 0.f;
    #pragma unroll
    for (int j=0;j<4;++j){ v[j] = b2f(loc[j]); s += v[j]; q += v[j]*v[j]; }
    #pragma unroll
    for (int o=1;o<64;o<<=1){ s += __shfl_xor(s, o); q += __shfl_xor(q, o); }
    __shared__ float sh[8];
    if (lane == 0){ sh[wave] = s; sh[4+wave] = q; }
    __syncthreads();
    s = sh[0]+sh[1]+sh[2]+sh[3];
    q = sh[4]+sh[5]+sh[6]+sh[7];
    float mu  = s * (1.f/1024.f);
    float var = q * (1.f/1024.f) - mu*mu;
    float rstd = rsqrtf(var + 1e-5f);
    int2 oraw;
    bf16* ob = (bf16*)&oraw;
    #pragma unroll
    for (int j=0;j<4;++j){
        float g = gamma[tid*4+j], be = beta[tid*4+j];
        ob[j] = f2b((v[j]-mu)*rstd*g + be);
    }
    *(int2*)(out + (size_t)row*1024 + tid*4) = oraw;
}

// ---------------- launch ----------------
extern "C" void kernel_launch(void* const* d_in, const int* in_sizes, int n_in,
                              void* d_out, int out_size, void* d_ws, size_t ws_size,
                              hipStream_t stream)
{
    const float* x     = (const float*)d_in[0];
    const float* rope  = (const float*)d_in[1];
    const float* Wqkv  = (const float*)d_in[2];
    const float* bqkv  = (const float*)d_in[3];
    const float* Wproj = (const float*)d_in[4];
    const float* bproj = (const float*)d_in[5];
    const float* lng   = (const float*)d_in[6];
    const float* lnb   = (const float*)d_in[7];
    float* out = (float*)d_out;

    char* ws = (char*)d_ws;
    size_t off = 0;
    auto alloc = [&](size_t bytes)->char* {
        char* p = ws + off;
        off += (bytes + 255) & ~(size_t)255;
        return p;
    };
    bf16* xhi    = (bf16*)alloc((size_t)M_*C_*2);
    bf16* xlo    = (bf16*)alloc((size_t)M_*C_*2);
    bf16* WqkvT  = (bf16*)alloc((size_t)3*C_*C_*2);
    bf16* WprojT = (bf16*)alloc((size_t)C_*C_*2);
    bf16* qkv    = (bf16*)alloc((size_t)M_*3*C_*2);
    bf16* attn   = xhi;   // reuse: xhi dead after GEMM1
    bf16* y      = xlo;   // reuse: xlo dead after GEMM1

    cvt_split<<<M_*C_/1024, 256, 0, stream>>>(x, xhi, xlo, M_*C_);
    transpose_cvt<<<dim3(3*C_/32, C_/32), dim3(32,8), 0, stream>>>(Wqkv, WqkvT, C_, 3*C_);
    transpose_cvt<<<dim3(C_/32, C_/32), dim3(32,8), 0, stream>>>(Wproj, WprojT, C_, C_);
    gemm_bt<bf16, true><<<dim3(3*C_/128, (M_+127)/128), 256, 0, stream>>>(
        xhi, xlo, WqkvT, bqkv, qkv, M_, 3*C_, C_);
    rope_kernel<<<(M_*H_*32)/256, 256, 0, stream>>>(qkv, rope);
    attn_kernel<<<dim3((L_+127)/128, B_*H_), 256, 0, stream>>>(qkv, attn);
    ln_kernel<<<M_, 256, 0, stream>>>(attn, lng, lnb, y);
    gemm_bt<float, false><<<dim3(C_/128, (M_+127)/128), 256, 0, stream>>>(
        y, nullptr, WprojT, bproj, out, M_, C_, C_);
}

// Round 5
// 511.355 us; speedup vs baseline: 1.3729x; 1.3729x over previous
//
#include <hip/hip_runtime.h>
#include <hip/hip_bf16.h>

#define B_ 4
#define L_ 2052
#define C_ 1024
#define H_ 16
#define D_ 64
#define NREG_ 4
#define M_ (B_*L_)     // 8208
#define LP_ 2056       // padded L stride for Vt (16B-aligned rows)
#define QSC 0.18033688f  // 0.125 * log2(e), applied in fp32 inside attn

typedef short bf16x8 __attribute__((ext_vector_type(8)));
typedef float f32x4 __attribute__((ext_vector_type(4)));
typedef __hip_bfloat16 bf16;

#define MFMA(a,b,c) __builtin_amdgcn_mfma_f32_16x16x32_bf16(a,b,c,0,0,0)

__device__ inline float b2f(bf16 v){ return __bfloat162float(v); }
__device__ inline bf16  f2b(float v){ return __float2bfloat16(v); }

// ---------------- x -> bf16 hi/lo split ----------------
__global__ __launch_bounds__(256)
void cvt_split(const float* __restrict__ in, bf16* __restrict__ hi,
               bf16* __restrict__ lo, int n)
{
    int i = (blockIdx.x*256 + threadIdx.x)*4;
    if (i >= n) return;
    float4 v = *(const float4*)(in + i);
    int2 hraw, lraw;
    bf16* hp = (bf16*)&hraw;
    bf16* lp = (bf16*)&lraw;
    float vv[4] = {v.x, v.y, v.z, v.w};
    #pragma unroll
    for (int j=0;j<4;++j){
        bf16 h = f2b(vv[j]);
        hp[j] = h;
        lp[j] = f2b(vv[j] - b2f(h));
    }
    *(int2*)(hi + i) = hraw;
    *(int2*)(lo + i) = lraw;
}

// ---------------- fp32 [R][Cc] -> bf16 transposed [Cc][R] ----------------
__global__ __launch_bounds__(256)
void transpose_cvt(const float* __restrict__ in, bf16* __restrict__ out,
                   int R, int Cc)
{
    __shared__ bf16 t[32][33];
    int bx = blockIdx.x * 32;
    int by = blockIdx.y * 32;
    int tx = threadIdx.x;
    int ty = threadIdx.y;
    #pragma unroll
    for (int i=0;i<4;++i){
        int r = by + ty + i*8;
        int c = bx + tx;
        t[ty+i*8][tx] = f2b(in[(size_t)r*Cc + c]);
    }
    __syncthreads();
    #pragma unroll
    for (int i=0;i<4;++i){
        int r = bx + ty + i*8;
        int c = by + tx;
        out[(size_t)r*R + c] = t[tx][ty+i*8];
    }
}

// ---------------- GEMM: A[M][K] (+optional lo) x Bt[N][K] -> C[M][N] ----------------
template<typename OutT, bool SPLIT>
__global__ __launch_bounds__(256)
void gemm_bt(const bf16* __restrict__ A, const bf16* __restrict__ Alo,
             const bf16* __restrict__ Bt, const float* __restrict__ bias,
             OutT* __restrict__ C, int M, int N, int K)
{
    __shared__ bf16 As[128*40];
    __shared__ bf16 Als[SPLIT ? 128*40 : 8];
    __shared__ bf16 Bs[128*40];

    int tid  = threadIdx.x;
    int lane = tid & 63, wave = tid >> 6;
    int wm = (wave>>1)*64, wn = (wave&1)*64;
    int bm = blockIdx.y*128, bn = blockIdx.x*128;
    int lrow = lane & 15, lk8 = (lane>>4)*8;
    int quad = lane >> 4;

    f32x4 acc[4][4] = {};

    int r0 = tid >> 2;
    int c0 = (tid & 3) * 8;

    for (int k0 = 0; k0 < K; k0 += 32) {
        #pragma unroll
        for (int it=0; it<2; ++it) {
            int r = r0 + it*64;
            int ga = bm + r;
            int4 va = {0,0,0,0}, vl = {0,0,0,0}, vb = {0,0,0,0};
            if (ga < M) {
                va = *(const int4*)(A + (size_t)ga*K + k0 + c0);
                if constexpr (SPLIT)
                    vl = *(const int4*)(Alo + (size_t)ga*K + k0 + c0);
            }
            int gb = bn + r;
            if (gb < N) vb = *(const int4*)(Bt + (size_t)gb*K + k0 + c0);
            *(int4*)(&As[r*40 + c0]) = va;
            if constexpr (SPLIT) *(int4*)(&Als[r*40 + c0]) = vl;
            *(int4*)(&Bs[r*40 + c0]) = vb;
        }
        __syncthreads();
        bf16x8 a[4], al[4], b[4];
        #pragma unroll
        for (int i=0;i<4;++i){
            a[i] = *(const bf16x8*)(&As[(wm+i*16+lrow)*40 + lk8]);
            if constexpr (SPLIT)
                al[i] = *(const bf16x8*)(&Als[(wm+i*16+lrow)*40 + lk8]);
            b[i] = *(const bf16x8*)(&Bs[(wn+i*16+lrow)*40 + lk8]);
        }
        #pragma unroll
        for (int mi=0;mi<4;++mi)
            #pragma unroll
            for (int ni=0;ni<4;++ni){
                acc[mi][ni] = MFMA(a[mi], b[ni], acc[mi][ni]);
                if constexpr (SPLIT)
                    acc[mi][ni] = MFMA(al[mi], b[ni], acc[mi][ni]);
            }
        __syncthreads();
    }

    #pragma unroll
    for (int ni=0;ni<4;++ni){
        int col = bn + wn + ni*16 + lrow;
        float bv = bias[col];
        #pragma unroll
        for (int mi=0;mi<4;++mi){
            int rowb = bm + wm + mi*16 + quad*4;
            #pragma unroll
            for (int r=0;r<4;++r){
                int row = rowb + r;
                if (row < M) {
                    float v = acc[mi][ni][r] + bv;
                    if constexpr (sizeof(OutT)==4) C[(size_t)row*N + col] = v;
                    else                           C[(size_t)row*N + col] = f2b(v);
                }
            }
        }
    }
}

// ---------------- RoPE in-place on q,k (pure rotation; NO scale fold) ----------------
__global__ __launch_bounds__(256)
void rope_kernel(bf16* __restrict__ qkv, const float* __restrict__ rope)
{
    int idx = blockIdx.x*256 + threadIdx.x;
    int d = idx & 31;
    int h = (idx >> 5) & 15;
    int m = idx >> 9;
    if (m >= M_) return;
    int l = m % L_;
    if (l < NREG_) return;
    const float* cp = rope + (size_t)(l - NREG_)*D_;
    const float* sp = rope + (size_t)(L_ - NREG_)*D_ + (size_t)(l - NREG_)*D_;
    float c0 = cp[d], c1 = cp[d+32], s0 = sp[d], s1 = sp[d+32];
    size_t base = (size_t)m*3072 + h*64;
    {
        float a = b2f(qkv[base + d]), b = b2f(qkv[base + d + 32]);
        qkv[base + d]      = f2b(a*c0 - b*s0);
        qkv[base + d + 32] = f2b(b*c1 + a*s1);
    }
    {
        size_t kb = base + 1024;
        float a = b2f(qkv[kb + d]), b = b2f(qkv[kb + d + 32]);
        qkv[kb + d]      = f2b(a*c0 - b*s0);
        qkv[kb + d + 32] = f2b(b*c1 + a*s1);
    }
}

// ---------------- V -> Vt [B*H][D][LP_] (zero-padded cols) ----------------
__global__ __launch_bounds__(256)
void transpose_v(const bf16* __restrict__ qkv, bf16* __restrict__ Vt)
{
    __shared__ bf16 t[64*72];
    int bh = blockIdx.y, lt = blockIdx.x;
    int b = bh >> 4, h = bh & 15;
    int tid = threadIdx.x;
    #pragma unroll
    for (int it=0; it<2; ++it){
        int i = tid + it*256;
        int il = i >> 3, c = (i&7)*8;
        int l = lt*64 + il;
        int4 v = {0,0,0,0};
        if (l < L_) v = *(const int4*)(qkv + ((size_t)b*L_ + l)*3072 + 2048 + h*64 + c);
        *(int4*)(&t[il*72 + c]) = v;
    }
    __syncthreads();
    #pragma unroll
    for (int it=0; it<2; ++it){
        int i = tid + it*256;
        int d = i >> 3, ck = (i&7)*8;
        if (lt*64 + ck + 8 <= LP_){
            union { int4 q; bf16 e[8]; } u;
            #pragma unroll
            for (int j=0;j<8;++j) u.e[j] = t[(ck+j)*72 + d];
            *(int4*)(&Vt[((size_t)bh*64 + d)*LP_ + lt*64 + ck]) = u.q;
        }
    }
}

// ---------------- flash attention (no online max; fp32 out) ----------------
// grid: (ceil(L/128), B*H), block 256 (4 waves, 32 Q-rows each)
__global__ __launch_bounds__(256)
void attn_kernel(const bf16* __restrict__ qkv, const bf16* __restrict__ Vt,
                 float* __restrict__ out)
{
    __shared__ bf16 sQP[10752];   // Q tile [128][72], then P: 4 waves x [32][84]
    __shared__ bf16 sK[64*72];
    __shared__ bf16 sV[64*72];    // [d][key]

    int tid = threadIdx.x, lane = tid & 63, wave = tid >> 6;
    int lrow = lane & 15, lk8 = (lane>>4)*8, quad = lane >> 4;
    int qt = blockIdx.x, bh = blockIdx.y;
    int b  = bh >> 4, h = bh & 15;
    size_t rowbase = (size_t)b * L_;
    int q0 = qt * 128;

    // stage Q tile
    #pragma unroll
    for (int it=0; it<4; ++it){
        int i = tid + it*256;
        int r = i >> 3;
        int c = (i & 7) * 8;
        int lq = q0 + r;
        int4 v = {0,0,0,0};
        if (lq < L_) v = *(const int4*)(qkv + (rowbase + lq)*3072 + h*64 + c);
        *(int4*)(&sQP[r*72 + c]) = v;
    }
    __syncthreads();

    bf16x8 qf[2][2];
    #pragma unroll
    for (int mi=0;mi<2;++mi)
        #pragma unroll
        for (int s=0;s<2;++s)
            qf[mi][s] = *(const bf16x8*)(&sQP[(wave*32 + mi*16 + lrow)*72 + s*32 + lk8]);

    float lst[2][4];
    f32x4 o_[2][4] = {};
    #pragma unroll
    for (int mi=0;mi<2;++mi)
        #pragma unroll
        for (int r=0;r<4;++r) lst[mi][r] = 0.f;

    bf16* pw = &sQP[wave*2688];   // per-wave P buffer [32][84]
    const int nkt = (L_ + 63) / 64;   // 33

    // prefetch tile 0 into registers
    int4 kr[2], vr[2];
    {
        #pragma unroll
        for (int it=0; it<2; ++it){
            int i = tid + it*256;
            int r = i >> 3, c = (i & 7)*8;
            int lk = r;
            kr[it] = (lk < L_) ? *(const int4*)(qkv + (rowbase+lk)*3072 + 1024 + h*64 + c)
                               : (int4){0,0,0,0};
            vr[it] = *(const int4*)(Vt + ((size_t)bh*64 + r)*LP_ + c);
        }
    }

    for (int kt = 0; kt < nkt; ++kt) {
        __syncthreads();   // LDS free (prev readers done)
        #pragma unroll
        for (int it=0; it<2; ++it){
            int i = tid + it*256;
            int r = i >> 3, c = (i & 7)*8;
            *(int4*)(&sK[r*72 + c]) = kr[it];
            *(int4*)(&sV[r*72 + c]) = vr[it];
        }
        __syncthreads();
        // prefetch next tile (overlaps with compute below)
        if (kt+1 < nkt){
            #pragma unroll
            for (int it=0; it<2; ++it){
                int i = tid + it*256;
                int r = i >> 3, c = (i & 7)*8;
                int lk = (kt+1)*64 + r;
                kr[it] = (lk < L_) ? *(const int4*)(qkv + (rowbase+lk)*3072 + 1024 + h*64 + c)
                                   : (int4){0,0,0,0};
                int vc = (kt+1)*64 + c;
                vr[it] = (vc + 8 <= LP_) ? *(const int4*)(Vt + ((size_t)bh*64 + r)*LP_ + vc)
                                         : (int4){0,0,0,0};
            }
        }

        // S = Q K^T  (raw; scale applied in fp32 below)
        f32x4 sf[2][4];
        {
            bf16x8 kf[4][2];
            #pragma unroll
            for (int ni=0;ni<4;++ni)
                #pragma unroll
                for (int s=0;s<2;++s)
                    kf[ni][s] = *(const bf16x8*)(&sK[(ni*16+lrow)*72 + s*32 + lk8]);
            #pragma unroll
            for (int mi=0;mi<2;++mi)
                #pragma unroll
                for (int ni=0;ni<4;++ni){
                    f32x4 t = {};
                    t = MFMA(qf[mi][0], kf[ni][0], t);
                    t = MFMA(qf[mi][1], kf[ni][1], t);
                    sf[mi][ni] = t;
                }
        }

        // p = 2^(s*QSC) (masked), accumulate per-lane row sums, write P to LDS
        #pragma unroll
        for (int ni=0;ni<4;++ni){
            int col = kt*64 + ni*16 + lrow;
            bool valid = col < L_;
            #pragma unroll
            for (int mi=0;mi<2;++mi)
                #pragma unroll
                for (int r=0;r<4;++r){
                    float p = valid ? __builtin_amdgcn_exp2f(sf[mi][ni][r]*QSC) : 0.f;
                    lst[mi][r] += p;
                    pw[(mi*16 + quad*4 + r)*84 + ni*16 + lrow] = f2b(p);
                }
        }

        // O += P V
        bf16x8 vf[4][2];
        #pragma unroll
        for (int ni=0;ni<4;++ni)
            #pragma unroll
            for (int s=0;s<2;++s)
                vf[ni][s] = *(const bf16x8*)(&sV[(ni*16+lrow)*72 + s*32 + lk8]);
        bf16x8 pf[2][2];
        #pragma unroll
        for (int mi=0;mi<2;++mi)
            #pragma unroll
            for (int s=0;s<2;++s){
                union { int2 h2[2]; bf16x8 v; } u;
                const bf16* pp = &pw[(mi*16 + lrow)*84 + s*32 + lk8];
                u.h2[0] = *(const int2*)(pp);
                u.h2[1] = *(const int2*)(pp + 4);
                pf[mi][s] = u.v;
            }
        #pragma unroll
        for (int mi=0;mi<2;++mi)
            #pragma unroll
            for (int ni=0;ni<4;++ni){
                f32x4 t = o_[mi][ni];
                t = MFMA(pf[mi][0], vf[ni][0], t);
                t = MFMA(pf[mi][1], vf[ni][1], t);
                o_[mi][ni] = t;
            }
    }

    // reduce row sums, finalize, store fp32
    #pragma unroll
    for (int mi=0;mi<2;++mi)
        #pragma unroll
        for (int r=0;r<4;++r){
            float s = lst[mi][r];
            #pragma unroll
            for (int o=1;o<16;o<<=1) s += __shfl_xor(s, o);
            float inv = 1.f / s;
            int lq = q0 + wave*32 + mi*16 + quad*4 + r;
            if (lq < L_){
                size_t base = (rowbase + lq)*1024 + h*64;
                #pragma unroll
                for (int ni=0;ni<4;++ni)
                    out[base + ni*16 + lrow] = o_[mi][ni][r]*inv;
            }
        }
}

// ---------------- LayerNorm (fp32 in) -> bf16 hi/lo split ----------------
__global__ __launch_bounds__(256)
void ln_kernel(const float* __restrict__ in, const float* __restrict__ gamma,
               const float* __restrict__ beta, bf16* __restrict__ yhi,
               bf16* __restrict__ ylo)
{
    int row = blockIdx.x;
    int tid = threadIdx.x;
    int wave = tid >> 6, lane = tid & 63;
    float4 v4 = *(const float4*)(in + (size_t)row*1024 + tid*4);
    float v[4] = {v4.x, v4.y, v4.z, v4.w};
    float s = 0.f, q = 0.f;
    #pragma unroll
    for (int j=0;j<4;++j){ s += v[j]; q += v[j]*v[j]; }
    #pragma unroll
    for (int o=1;o<64;o<<=1){ s += __shfl_xor(s, o); q += __shfl_xor(q, o); }
    __shared__ float sh[8];
    if (lane == 0){ sh[wave] = s; sh[4+wave] = q; }
    __syncthreads();
    s = sh[0]+sh[1]+sh[2]+sh[3];
    q = sh[4]+sh[5]+sh[6]+sh[7];
    float mu  = s * (1.f/1024.f);
    float var = q * (1.f/1024.f) - mu*mu;
    float rstd = rsqrtf(var + 1e-5f);
    int2 hraw, lraw;
    bf16* hb = (bf16*)&hraw;
    bf16* lb = (bf16*)&lraw;
    #pragma unroll
    for (int j=0;j<4;++j){
        float g = gamma[tid*4+j], be = beta[tid*4+j];
        float y = (v[j]-mu)*rstd*g + be;
        bf16 hh = f2b(y);
        hb[j] = hh;
        lb[j] = f2b(y - b2f(hh));
    }
    *(int2*)(yhi + (size_t)row*1024 + tid*4) = hraw;
    *(int2*)(ylo + (size_t)row*1024 + tid*4) = lraw;
}

// ---------------- launch ----------------
extern "C" void kernel_launch(void* const* d_in, const int* in_sizes, int n_in,
                              void* d_out, int out_size, void* d_ws, size_t ws_size,
                              hipStream_t stream)
{
    const float* x     = (const float*)d_in[0];
    const float* rope  = (const float*)d_in[1];
    const float* Wqkv  = (const float*)d_in[2];
    const float* bqkv  = (const float*)d_in[3];
    const float* Wproj = (const float*)d_in[4];
    const float* bproj = (const float*)d_in[5];
    const float* lng   = (const float*)d_in[6];
    const float* lnb   = (const float*)d_in[7];
    float* out = (float*)d_out;

    char* ws = (char*)d_ws;
    size_t off = 0;
    auto alloc = [&](size_t bytes)->char* {
        char* p = ws + off;
        off += (bytes + 255) & ~(size_t)255;
        return p;
    };
    bf16* xhi    = (bf16*)alloc((size_t)M_*C_*2);
    bf16* xlo    = (bf16*)alloc((size_t)M_*C_*2);
    bf16* WqkvT  = (bf16*)alloc((size_t)3*C_*C_*2);
    bf16* WprojT = (bf16*)alloc((size_t)C_*C_*2);
    bf16* qkv    = (bf16*)alloc((size_t)M_*3*C_*2);
    bf16* Vt     = (bf16*)alloc((size_t)B_*H_*D_*LP_*2);

    float* attnF = (float*)xhi;        // xhi+xlo region = exactly M*C*4 bytes
    bf16*  yhi   = qkv;                // qkv dead after attention
    bf16*  ylo   = qkv + (size_t)M_*C_;

    cvt_split<<<M_*C_/1024, 256, 0, stream>>>(x, xhi, xlo, M_*C_);
    transpose_cvt<<<dim3(3*C_/32, C_/32), dim3(32,8), 0, stream>>>(Wqkv, WqkvT, C_, 3*C_);
    transpose_cvt<<<dim3(C_/32, C_/32), dim3(32,8), 0, stream>>>(Wproj, WprojT, C_, C_);
    gemm_bt<bf16, true><<<dim3(3*C_/128, (M_+127)/128), 256, 0, stream>>>(
        xhi, xlo, WqkvT, bqkv, qkv, M_, 3*C_, C_);
    rope_kernel<<<(M_*H_*32)/256, 256, 0, stream>>>(qkv, rope);
    transpose_v<<<dim3((L_+63)/64, B_*H_), 256, 0, stream>>>(qkv, Vt);
    attn_kernel<<<dim3((L_+127)/128, B_*H_), 256, 0, stream>>>(qkv, Vt, attnF);
    ln_kernel<<<M_, 256, 0, stream>>>(attnF, lng, lnb, yhi, ylo);
    gemm_bt<float, true><<<dim3(C_/128, (M_+127)/128), 256, 0, stream>>>(
        yhi, ylo, WprojT, bproj, out, M_, C_, C_);
}